// Round 3
// baseline (344.542 us; speedup 1.0000x reference)
//
#include <hip/hip_runtime.h>
#include <math.h>

#define NUM_TAGS 20000
#define BATCH 64
#define H4 1024
#define HD 256
#define NT1 20001   // NUM_TAGS + 1

__device__ __forceinline__ float gelu_exact(float x) {
    return 0.5f * x * (1.0f + erff(x * 0.7071067811865476f));
}

// 4-byte-aligned float4 (A rows can be misaligned: lda=20001)
struct F4 { float x, y, z, w; };

// ---- async global->LDS (gfx950). LDS dest = wave-uniform base + lane*size.
typedef const __attribute__((address_space(1))) void* gp_t;
typedef __attribute__((address_space(3))) void* lp_t;
__device__ __forceinline__ void async_ld4(const float* g, float* lds_base) {
    __builtin_amdgcn_global_load_lds((gp_t)g, (lp_t)lds_base, 4, 0, 0);
}
__device__ __forceinline__ void async_ld16(const float* g, float* lds_base) {
    __builtin_amdgcn_global_load_lds((gp_t)g, (lp_t)lds_base, 16, 0, 0);
}

// ---------------- counts: scatter with per-(b,f) dedup ----------------
__global__ __launch_bounds__(128) void k_scatter(const int* __restrict__ tags,
                                                 int* __restrict__ counts) {
    int g = blockIdx.x * 128 + threadIdx.x;  // (b,f)
    int b = g >> 7;
    const int* tp = tags + ((size_t)g << 4);
    int t[16];
#pragma unroll
    for (int i = 0; i < 16; ++i) t[i] = tp[i];
#pragma unroll
    for (int i = 0; i < 16; ++i) {
        bool dup = false;
        for (int j = 0; j < i; ++j) dup = dup || (t[j] == t[i]);
        if (!dup) atomicAdd(&counts[(size_t)b * NUM_TAGS + t[i]], 1);
    }
}

// ---------------- LN1 phase A: partial stats ----------------
__global__ __launch_bounds__(256) void k_ln1_stats(const int* __restrict__ counts,
                                                   float* __restrict__ stats) {
    int b = blockIdx.y, c = blockIdx.x, tid = threadIdx.x;
    const int* crow = counts + (size_t)b * NUM_TAGS;
    int lo = c * 2500, hi = lo + 2500;
    float s = 0.f, s2 = 0.f;
    for (int t = lo + tid; t < hi; t += 256) {
        float v = (float)crow[t];
        s += v; s2 += v * v;
    }
#pragma unroll
    for (int off = 32; off > 0; off >>= 1) {
        s  += __shfl_down(s, off);
        s2 += __shfl_down(s2, off);
    }
    __shared__ float ls[4], ls2[4];
    int wave = tid >> 6;
    if ((tid & 63) == 0) { ls[wave] = s; ls2[wave] = s2; }
    __syncthreads();
    if (tid == 0) {
        stats[(b * 8 + c) * 2 + 0] = ls[0] + ls[1] + ls[2] + ls[3];
        stats[(b * 8 + c) * 2 + 1] = ls2[0] + ls2[1] + ls2[2] + ls2[3];
    }
}

// ---------------- LN1 phase B: apply ----------------
__global__ __launch_bounds__(256) void k_ln1_apply(const int* __restrict__ counts,
                                                   const float* __restrict__ fc,
                                                   const float* __restrict__ lng,
                                                   const float* __restrict__ lnb,
                                                   const float* __restrict__ stats,
                                                   float* __restrict__ y) {
    int b = blockIdx.y, c = blockIdx.x, tid = threadIdx.x;
    float S = 0.f, S2 = 0.f;
#pragma unroll
    for (int i = 0; i < 8; ++i) {
        S  += stats[(b * 8 + i) * 2 + 0];
        S2 += stats[(b * 8 + i) * 2 + 1];
    }
    float mu = S / (float)NUM_TAGS;
    float var = S2 / (float)NUM_TAGS - mu * mu;
    float rs = rsqrtf(var + 1e-5f);
    const int* crow = counts + (size_t)b * NUM_TAGS;
    float* yrow = y + (size_t)b * NT1;
    if (c == 0 && tid == 0) yrow[0] = fc[b] * 0.01f;
    int lo = c * 2500, hi = lo + 2500;
    for (int t = lo + tid; t < hi; t += 256) {
        float v = (float)crow[t];
        yrow[1 + t] = (v - mu) * rs * lng[t] + lnb[t];
    }
}

// ---------------- 8-wave wave-uniform-A split-K GEMM ------------------------
// P[(bx*KS+ky)][64][256] = A[64, kslice] @ W[kslice, 256cols]
// 512 thr = 8 waves. Wave w owns rows w*8..w*8+7 (all wave-uniform A values,
// loaded straight from global: same-address across the wave -> 1 transaction,
// L1-broadcast, 128B line reused across 4 chunks). Lane owns cols lane*4..+3.
// W staged in LDS via async DMA, double-buffered; ONE ds_read_b128 per k per
// thread (8 per chunk vs 32 in the old 4-wave layout -> LDS off critical path).
// acc[8] float4 = 32 VGPR. BK=8. Requires kpb % 8 == 0, all K-slices full.
// PATH 0: W rows 16B-aligned (ldw%4==0, N%256==0): 1 async_ld16/thread/chunk.
// PATH 1: dword W loads, col clamped to N-1 (odd ldw): 4 async_ld4/thread/chunk.
template <int PATH>
__global__ __launch_bounds__(512, 2) void k_gemm(const float* __restrict__ A, int lda,
                                                 const float* __restrict__ W, int ldw,
                                                 float* __restrict__ P,
                                                 int N, int kpb) {
    __shared__ __align__(16) float Ws[2][2048];   // [kk][col] : kk*256 + col
    const int tid = threadIdx.x;
    const int lane = tid & 63;
    const int wid = __builtin_amdgcn_readfirstlane(tid >> 6);
    const int wrow = wid * 8;
    const int n0 = blockIdx.x * 256;
    const int kstart = blockIdx.y * kpb;
    const int nchunk = kpb >> 3;

    float4 acc[8];
#pragma unroll
    for (int i = 0; i < 8; ++i) acc[i] = make_float4(0.f, 0.f, 0.f, 0.f);

    // ---- issue chunk c into buffer b (async DMA), W tile 8k x 256 cols ----
    auto issue = [&](int b, int c) {
        int k0 = kstart + c * 8;
        if (PATH == 0) {
            // 512 granules of 16B; g = tid -> kk=g>>6, c4=g&63
            int kk = tid >> 6, c4 = tid & 63;
            async_ld16(W + (size_t)(k0 + kk) * ldw + n0 + c4 * 4, &Ws[b][wid * 256]);
        } else {
            // 2048 dwords; d = j*512+tid -> kk=d>>8, cc=d&255 (col clamped)
#pragma unroll
            for (int j = 0; j < 4; ++j) {
                int d = j * 512 + tid;
                int kk = d >> 8, cc = d & 255;
                async_ld4(W + (size_t)(k0 + kk) * ldw + min(n0 + cc, N - 1),
                          &Ws[b][j * 512 + wid * 64]);
            }
        }
    };

    issue(0, 0);

    for (int c = 0; c < nchunk; ++c) {
        __syncthreads();                 // drains vmcnt -> buf[c&1] ready
        if (c + 1 < nchunk) issue((c + 1) & 1, c + 1);  // flies during compute
        const float* Wb = Ws[c & 1];
        const int k0 = kstart + c * 8;
        __builtin_amdgcn_s_setprio(1);
#pragma unroll
        for (int k4 = 0; k4 < 2; ++k4) {
            F4 a[8];
#pragma unroll
            for (int i = 0; i < 8; ++i)
                a[i] = *(const F4*)(A + (size_t)(wrow + i) * lda + k0 + k4 * 4);
#pragma unroll
            for (int kl = 0; kl < 4; ++kl) {
                const float4 w = *(const float4*)&Wb[(k4 * 4 + kl) * 256 + lane * 4];
#pragma unroll
                for (int i = 0; i < 8; ++i) {
                    float av = (kl == 0) ? a[i].x : (kl == 1) ? a[i].y
                             : (kl == 2) ? a[i].z : a[i].w;
                    acc[i].x = fmaf(av, w.x, acc[i].x);
                    acc[i].y = fmaf(av, w.y, acc[i].y);
                    acc[i].z = fmaf(av, w.z, acc[i].z);
                    acc[i].w = fmaf(av, w.w, acc[i].w);
                }
            }
        }
        __builtin_amdgcn_s_setprio(0);
    }

    float* Pp = P + ((size_t)blockIdx.x * gridDim.y + blockIdx.y) * 16384;
#pragma unroll
    for (int i = 0; i < 8; ++i)
        *(float4*)&Pp[(wrow + i) * 256 + lane * 4] = acc[i];
}

// ---------------- reduce partials + bias (+rank-1 fc term) (+gelu) ---------
template <bool GELU>
__global__ __launch_bounds__(256) void k_reduce(const float* __restrict__ P, int KS,
                                                const float* __restrict__ bias,
                                                const float* __restrict__ r1row,
                                                const float* __restrict__ fc,
                                                float* __restrict__ out, int ldo, int N) {
    int b = blockIdx.y;
    int n = blockIdx.x * 256 + threadIdx.x;
    if (n >= N) return;
    int nb = n >> 8, col = n & 255;
    const float* p = P + (size_t)nb * KS * 16384 + b * 256 + col;
    float s0 = 0.f, s1 = 0.f, s2 = 0.f, s3 = 0.f;
    int k = 0;
    for (; k + 3 < KS; k += 4) {
        s0 += p[(size_t)(k + 0) * 16384];
        s1 += p[(size_t)(k + 1) * 16384];
        s2 += p[(size_t)(k + 2) * 16384];
        s3 += p[(size_t)(k + 3) * 16384];
    }
    for (; k < KS; ++k) s0 += p[(size_t)k * 16384];
    float s = (s0 + s1) + (s2 + s3) + bias[n];
    if (r1row) s += fc[b] * 0.01f * r1row[n];
    if (GELU) s = gelu_exact(s);
    out[(size_t)b * ldo + n] = s;
}

// ---------------- vectorized reduce (bias only, no gelu) for wide N --------
__global__ __launch_bounds__(256) void k_reduce_v4(const float* __restrict__ P, int KS,
                                                   const float* __restrict__ bias,
                                                   float* __restrict__ out, int ldo, int N) {
    int b = blockIdx.y;
    int n = (blockIdx.x * 256 + threadIdx.x) * 4;
    if (n >= N) return;
    int nb = n >> 8, col = n & 255;
    const float* p = P + (size_t)nb * KS * 16384 + b * 256 + col;
    if (n + 3 < N) {
        float sx = 0.f, sy = 0.f, sz = 0.f, sw = 0.f;
        for (int k = 0; k < KS; ++k) {
            float4 v = *(const float4*)&p[(size_t)k * 16384];
            sx += v.x; sy += v.y; sz += v.z; sw += v.w;
        }
        F4 bi = *(const F4*)&bias[n];
        F4 r = {sx + bi.x, sy + bi.y, sz + bi.z, sw + bi.w};
        *(F4*)&out[(size_t)b * ldo + n] = r;   // ldo may be odd -> 4B-aligned store
    } else {
        for (int j = 0; n + j < N; ++j) {
            float s = 0.f;
            for (int k = 0; k < KS; ++k) s += p[(size_t)k * 16384 + j];
            out[(size_t)b * ldo + n + j] = s + bias[n + j];
        }
    }
}

// ---------------- LN2: one block per row (1024 cols) ----------------
__global__ __launch_bounds__(256) void k_ln2(const float* __restrict__ g1,
                                             const float* __restrict__ lng,
                                             const float* __restrict__ lnb,
                                             float* __restrict__ h2) {
    int b = blockIdx.x, tid = threadIdx.x;
    float v[4];
    float s = 0.f, s2 = 0.f;
#pragma unroll
    for (int j = 0; j < 4; ++j) {
        int nidx = tid + 256 * j;
        float x = g1[b * H4 + nidx];
        v[j] = x;
        s += x; s2 += x * x;
    }
#pragma unroll
    for (int off = 32; off > 0; off >>= 1) {
        s  += __shfl_down(s, off);
        s2 += __shfl_down(s2, off);
    }
    __shared__ float ls[4], ls2[4], smu, srs;
    int wave = tid >> 6;
    if ((tid & 63) == 0) { ls[wave] = s; ls2[wave] = s2; }
    __syncthreads();
    if (tid == 0) {
        float S  = ls[0] + ls[1] + ls[2] + ls[3];
        float S2 = ls2[0] + ls2[1] + ls2[2] + ls2[3];
        float mu = S / (float)H4;
        float var = S2 / (float)H4 - mu * mu;
        smu = mu;
        srs = rsqrtf(var + 1e-5f);
    }
    __syncthreads();
    float mu = smu, rs = srs;
#pragma unroll
    for (int j = 0; j < 4; ++j) {
        int nidx = tid + 256 * j;
        h2[b * H4 + nidx] = (v[j] - mu) * rs * lng[nidx] + lnb[nidx];
    }
}

// ---------------- launch ----------------
extern "C" void kernel_launch(void* const* d_in, const int* in_sizes, int n_in,
                              void* d_out, int out_size, void* d_ws, size_t ws_size,
                              hipStream_t stream) {
    (void)in_sizes; (void)n_in; (void)out_size;
    const int*   tags  = (const int*)d_in[0];
    const float* fc    = (const float*)d_in[1];
    const float* ln_g  = (const float*)d_in[2];
    const float* ln_b  = (const float*)d_in[3];
    const float* w1    = (const float*)d_in[4];
    const float* b1    = (const float*)d_in[5];
    const float* ln2_g = (const float*)d_in[6];
    const float* ln2_b = (const float*)d_in[7];
    const float* we1   = (const float*)d_in[8];
    const float* be1   = (const float*)d_in[9];
    const float* we2   = (const float*)d_in[10];
    const float* be2   = (const float*)d_in[11];
    const float* wd1   = (const float*)d_in[12];
    const float* bd1   = (const float*)d_in[13];
    const float* wd2   = (const float*)d_in[14];
    const float* bd2   = (const float*)d_in[15];

    float* out = (float*)d_out;
    float* y   = out;                              // 64*20001
    float* enc = out + (size_t)BATCH * NT1;        // 64*256
    float* dec = enc + BATCH * HD;                 // 64*20001

    char* ws = (char*)d_ws;
    size_t off = 0;
    int*   counts = (int*)(ws + off);   off += (size_t)BATCH * NUM_TAGS * 4;  // 5.12 MB
    float* stats  = (float*)(ws + off); off += 64 * 8 * 2 * 4;
    float* g1     = (float*)(ws + off); off += (size_t)BATCH * H4 * 4;
    float* h2     = (float*)(ws + off); off += (size_t)BATCH * H4 * 4;
    float* g2     = (float*)(ws + off); off += (size_t)BATCH * H4 * 4;
    float* dd     = (float*)(ws + off); off += (size_t)BATCH * H4 * 4;
    float* arena  = (float*)(ws + off);
    size_t avail  = (ws_size > off) ? (ws_size - off) : 0;

    // split-K tiers (ws_size constant across calls -> deterministic)
    const size_t MB = 1024 * 1024;
    int KS1, KS5;
    if (avail >= 45 * MB)      { KS1 = 125; KS5 = 8; }   // arenas 32.8 / 41.4 MB
    else if (avail >= 33 * MB) { KS1 = 125; KS5 = 4; }
    else if (avail >= 17 * MB) { KS1 = 63;  KS5 = 4; }
    else                       { KS1 = 63;  KS5 = 2; }
    int kpb5 = H4 / KS5;
    (void)KS1;

    hipMemsetAsync(counts, 0, (size_t)BATCH * NUM_TAGS * 4, stream);
    k_scatter<<<64, 128, 0, stream>>>(tags, counts);
    k_ln1_stats<<<dim3(8, 64), 256, 0, stream>>>(counts, stats);
    k_ln1_apply<<<dim3(8, 64), 256, 0, stream>>>(counts, fc, ln_g, ln_b, stats, y);

    // GEMM1: yn[64,20000] @ w1[1:,1024]; fc-column folded into reduce as rank-1
    k_gemm<0><<<dim3(4, 125), 512, 0, stream>>>(y + 1, NT1, w1 + H4, H4, arena, H4, 160);
    k_reduce<true><<<dim3(4, 64), 256, 0, stream>>>(arena, 125, b1, w1, fc, g1, H4, H4);
    k_ln2<<<64, 256, 0, stream>>>(g1, ln2_g, ln2_b, h2);

    // GEMM2: h2 @ we1[1024,1024]
    k_gemm<0><<<dim3(4, 32), 512, 0, stream>>>(h2, H4, we1, H4, arena, H4, 32);
    k_reduce<true><<<dim3(4, 64), 256, 0, stream>>>(arena, 32, be1, nullptr, nullptr, g2, H4, H4);

    // GEMM3: g2 @ we2[1024,256]
    k_gemm<0><<<dim3(1, 32), 512, 0, stream>>>(g2, H4, we2, HD, arena, HD, 32);
    k_reduce<false><<<dim3(1, 64), 256, 0, stream>>>(arena, 32, be2, nullptr, nullptr, enc, HD, HD);

    // GEMM4: enc @ wd1[256,1024]
    k_gemm<0><<<dim3(4, 16), 512, 0, stream>>>(enc, HD, wd1, H4, arena, H4, 16);
    k_reduce<true><<<dim3(4, 64), 256, 0, stream>>>(arena, 16, bd1, nullptr, nullptr, dd, H4, H4);

    // GEMM5: dd @ wd2[1024,20001]  (odd ldw -> PATH 1)
    k_gemm<1><<<dim3(79, KS5), 512, 0, stream>>>(dd, H4, wd2, NT1, arena, NT1, kpb5);
    k_reduce_v4<<<dim3(20, 64), 256, 0, stream>>>(arena, KS5, bd2, dec, NT1, NT1);
}

// Round 4
// 320.102 us; speedup vs baseline: 1.0763x; 1.0763x over previous
//
#include <hip/hip_runtime.h>
#include <math.h>

#define NUM_TAGS 20000
#define BATCH 64
#define H4 1024
#define HD 256
#define NT1 20001   // NUM_TAGS + 1

__device__ __forceinline__ float gelu_exact(float x) {
    return 0.5f * x * (1.0f + erff(x * 0.7071067811865476f));
}

// 4-byte-aligned float4 (rows can be misaligned: ld=20001)
struct F4 { float x, y, z, w; };

// ---- async global->LDS (gfx950). LDS dest = wave-uniform base + lane*size.
typedef const __attribute__((address_space(1))) void* gp_t;
typedef __attribute__((address_space(3))) void* lp_t;
__device__ __forceinline__ void async_ld4(const float* g, float* lds_base) {
    __builtin_amdgcn_global_load_lds((gp_t)g, (lp_t)lds_base, 4, 0, 0);
}
__device__ __forceinline__ void async_ld16(const float* g, float* lds_base) {
    __builtin_amdgcn_global_load_lds((gp_t)g, (lp_t)lds_base, 16, 0, 0);
}

// ---------- fused: scatter(dedup) + LN1 stats + LN1 apply, all in LDS -------
// One block per batch row b. 20000-bin histogram lives in LDS (80 KB);
// no global counts buffer, no memset, no global atomics, no re-reads.
__global__ __launch_bounds__(1024) void k_ln1_fused(const int* __restrict__ tags,
                                                    const float* __restrict__ fc,
                                                    const float* __restrict__ lng,
                                                    const float* __restrict__ lnb,
                                                    float* __restrict__ y) {
    __shared__ int hist[NUM_TAGS];
    __shared__ float ls[16], ls2[16], smu, srs;
    const int b = blockIdx.x, tid = threadIdx.x;

    // zero histogram
    for (int t = tid; t < NUM_TAGS; t += 1024) hist[t] = 0;
    __syncthreads();

    // scatter: thread f (0..127) handles feature f's 16 tags with in-row dedup
    if (tid < 128) {
        const int* tp = tags + ((size_t)(b * 128 + tid) << 4);
        int t[16];
#pragma unroll
        for (int i = 0; i < 16; ++i) t[i] = tp[i];
#pragma unroll
        for (int i = 0; i < 16; ++i) {
            bool dup = false;
            for (int j = 0; j < i; ++j) dup = dup || (t[j] == t[i]);
            if (!dup) atomicAdd(&hist[t[i]], 1);
        }
    }
    __syncthreads();

    // stats over the 20000 counts
    float s = 0.f, s2 = 0.f;
    for (int t = tid; t < NUM_TAGS; t += 1024) {
        float v = (float)hist[t];
        s += v; s2 += v * v;
    }
#pragma unroll
    for (int off = 32; off > 0; off >>= 1) {
        s  += __shfl_down(s, off);
        s2 += __shfl_down(s2, off);
    }
    int wave = tid >> 6;
    if ((tid & 63) == 0) { ls[wave] = s; ls2[wave] = s2; }
    __syncthreads();
    if (tid == 0) {
        float S = 0.f, S2 = 0.f;
#pragma unroll
        for (int i = 0; i < 16; ++i) { S += ls[i]; S2 += ls2[i]; }
        float mu = S / (float)NUM_TAGS;
        float var = S2 / (float)NUM_TAGS - mu * mu;
        smu = mu;
        srs = rsqrtf(var + 1e-5f);
    }
    __syncthreads();
    float mu = smu, rs = srs;

    // apply + write y row
    float* yrow = y + (size_t)b * NT1;
    if (tid == 0) yrow[0] = fc[b] * 0.01f;
    for (int t = tid; t < NUM_TAGS; t += 1024) {
        float v = (float)hist[t];
        yrow[1 + t] = (v - mu) * rs * lng[t] + lnb[t];
    }
}

// ---------------- async 4-buffer deep-pipelined split-K GEMM ----------------
// P[(bx*KS+ky)][64][256] = A[64, kslice] @ W[kslice, 256cols]
// 256 thr: tn=tid&31 (cols tn*4..+3 and 128+tn*4..+3), tb=tid>>5 (8 rows each).
// BK=8, 4 LDS buffers, depth-2 prefetch, counted vmcnt (no full drain in loop).
// Requires: kpb % 8 == 0, all K-slices full.
// PATH 0: W rows 16B-aligned (ldw%4==0, N%256==0). PATH 1: dword W loads,
// col clamped to N-1 (odd ldw ok).
// Loads per thread per chunk L: PATH0 = 2(A)+2(W16) = 4; PATH1 = 2(A)+8(W4) = 10.
// launch_bounds(256,2): 84 VGPR / no spill (round-2 measured); (256,4) forced
// 64 VGPR -> 94 MB scratch spill (round-1 disaster). Keep (256,2).
template <int PATH>
__global__ __launch_bounds__(256, 2) void k_gemm(const float* __restrict__ A, int lda,
                                                 const float* __restrict__ W, int ldw,
                                                 float* __restrict__ P,
                                                 int N, int kpb) {
    __shared__ __align__(16) float As[4][512];    // [row][kk] : row*8 + kk
    __shared__ __align__(16) float Ws[4][2048];   // [kk][col] : kk*256 + col
    const int tid = threadIdx.x;
    const int lane = tid & 63, wid = tid >> 6;
    const int tn = tid & 31, tb = tid >> 5;
    const int n0 = blockIdx.x * 256;
    const int kstart = blockIdx.y * kpb;
    const int nchunk = kpb >> 3;

    float acc[8][8];
#pragma unroll
    for (int i = 0; i < 8; ++i)
#pragma unroll
        for (int j = 0; j < 8; ++j) acc[i][j] = 0.f;

    // ---- issue chunk c into buffer b (async DMA) ----
    auto issue = [&](int b, int c) {
        int k0 = kstart + c * 8;
        // A tile: 64x8 = 512 dwords; d -> row=d>>3, kk=d&7
#pragma unroll
        for (int j = 0; j < 2; ++j) {
            int d0 = j * 256 + wid * 64;
            int d = d0 + lane;
            async_ld4(A + (size_t)(d >> 3) * lda + k0 + (d & 7), &As[b][d0]);
        }
        if (PATH == 0) {
            // W tile: 8 rows x 256 cols = 512 16B-granules; g -> kk=g>>6, c4=g&63
#pragma unroll
            for (int j = 0; j < 2; ++j) {
                int g0 = j * 256 + wid * 64;
                int g = g0 + lane;
                int kk = g >> 6, c4 = g & 63;
                async_ld16(W + (size_t)(k0 + kk) * ldw + n0 + c4 * 4, &Ws[b][g0 * 4]);
            }
        } else {
            // W tile: 2048 dwords; d -> kk=d>>8, c=d&255 (col clamped)
#pragma unroll
            for (int j = 0; j < 8; ++j) {
                int d0 = j * 256 + wid * 64;
                int d = d0 + lane;
                int kk = d >> 8, cc = d & 255;
                async_ld4(W + (size_t)(k0 + kk) * ldw + min(n0 + cc, N - 1), &Ws[b][d0]);
            }
        }
    };

    issue(0, 0);
    if (nchunk > 1) issue(1, 1);

    for (int c = 0; c < nchunk; ++c) {
        if (c + 2 < nchunk) issue((c + 2) & 3, c + 2);
        // Counted wait: keep up to 2 chunks' loads in flight across the barrier.
        int ahead = nchunk - 1 - c;
        if (PATH == 0) {
            if (ahead >= 2)      asm volatile("s_waitcnt vmcnt(8)"  ::: "memory");
            else if (ahead == 1) asm volatile("s_waitcnt vmcnt(4)"  ::: "memory");
            else                 asm volatile("s_waitcnt vmcnt(0)"  ::: "memory");
        } else {
            if (ahead >= 2)      asm volatile("s_waitcnt vmcnt(20)" ::: "memory");
            else if (ahead == 1) asm volatile("s_waitcnt vmcnt(10)" ::: "memory");
            else                 asm volatile("s_waitcnt vmcnt(0)"  ::: "memory");
        }
        __builtin_amdgcn_s_barrier();          // all waves' chunk-c loads landed
        asm volatile("" ::: "memory");         // no LDS access hoisted above

        const float* Ab = As[c & 3];
        const float* Wb = Ws[c & 3];
        __builtin_amdgcn_s_setprio(1);
#pragma unroll
        for (int k4 = 0; k4 < 2; ++k4) {
            float4 a4[8];
#pragma unroll
            for (int i = 0; i < 8; ++i)
                a4[i] = *(const float4*)&Ab[(tb * 8 + i) * 8 + k4 * 4];
#pragma unroll
            for (int kl = 0; kl < 4; ++kl) {
                // lane-contiguous 16B reads -> conflict-free
                const float4 w0 = *(const float4*)&Wb[(k4 * 4 + kl) * 256 + tn * 4];
                const float4 w1 = *(const float4*)&Wb[(k4 * 4 + kl) * 256 + 128 + tn * 4];
                const float wv[8] = {w0.x, w0.y, w0.z, w0.w, w1.x, w1.y, w1.z, w1.w};
#pragma unroll
                for (int i = 0; i < 8; ++i) {
                    float av = (kl == 0) ? a4[i].x : (kl == 1) ? a4[i].y
                             : (kl == 2) ? a4[i].z : a4[i].w;
#pragma unroll
                    for (int jj = 0; jj < 8; ++jj)
                        acc[i][jj] = fmaf(av, wv[jj], acc[i][jj]);
                }
            }
        }
        __builtin_amdgcn_s_setprio(0);
        asm volatile("" ::: "memory");         // no LDS access sunk below
    }

    float* Pp = P + ((size_t)blockIdx.x * gridDim.y + blockIdx.y) * 16384;
#pragma unroll
    for (int i = 0; i < 8; ++i) {
        int row = tb * 8 + i;
        float4 v0 = {acc[i][0], acc[i][1], acc[i][2], acc[i][3]};
        float4 v1 = {acc[i][4], acc[i][5], acc[i][6], acc[i][7]};
        *(float4*)&Pp[row * 256 + tn * 4]       = v0;
        *(float4*)&Pp[row * 256 + 128 + tn * 4] = v1;
    }
}

// ---------------- reduce partials + bias (+rank-1 fc term) (+gelu) ---------
template <bool GELU>
__global__ __launch_bounds__(256) void k_reduce(const float* __restrict__ P, int KS,
                                                const float* __restrict__ bias,
                                                const float* __restrict__ r1row,
                                                const float* __restrict__ fc,
                                                float* __restrict__ out, int ldo, int N) {
    int b = blockIdx.y;
    int n = blockIdx.x * 256 + threadIdx.x;
    if (n >= N) return;
    int nb = n >> 8, col = n & 255;
    const float* p = P + (size_t)nb * KS * 16384 + b * 256 + col;
    float s0 = 0.f, s1 = 0.f, s2 = 0.f, s3 = 0.f;
    int k = 0;
    for (; k + 3 < KS; k += 4) {
        s0 += p[(size_t)(k + 0) * 16384];
        s1 += p[(size_t)(k + 1) * 16384];
        s2 += p[(size_t)(k + 2) * 16384];
        s3 += p[(size_t)(k + 3) * 16384];
    }
    for (; k < KS; ++k) s0 += p[(size_t)k * 16384];
    float s = (s0 + s1) + (s2 + s3) + bias[n];
    if (r1row) s += fc[b] * 0.01f * r1row[n];
    if (GELU) s = gelu_exact(s);
    out[(size_t)b * ldo + n] = s;
}

// ---------------- vectorized reduce (bias only, no gelu) for wide N --------
__global__ __launch_bounds__(256) void k_reduce_v4(const float* __restrict__ P, int KS,
                                                   const float* __restrict__ bias,
                                                   float* __restrict__ out, int ldo, int N) {
    int b = blockIdx.y;
    int n = (blockIdx.x * 256 + threadIdx.x) * 4;
    if (n >= N) return;
    int nb = n >> 8, col = n & 255;
    const float* p = P + (size_t)nb * KS * 16384 + b * 256 + col;
    if (n + 3 < N) {
        float sx = 0.f, sy = 0.f, sz = 0.f, sw = 0.f;
        for (int k = 0; k < KS; ++k) {
            float4 v = *(const float4*)&p[(size_t)k * 16384];
            sx += v.x; sy += v.y; sz += v.z; sw += v.w;
        }
        F4 bi = *(const F4*)&bias[n];
        F4 r = {sx + bi.x, sy + bi.y, sz + bi.z, sw + bi.w};
        *(F4*)&out[(size_t)b * ldo + n] = r;   // ldo odd -> 4B-aligned store
    } else {
        for (int j = 0; n + j < N; ++j) {
            float s = 0.f;
            for (int k = 0; k < KS; ++k) s += p[(size_t)k * 16384 + j];
            out[(size_t)b * ldo + n + j] = s + bias[n + j];
        }
    }
}

// ---------------- LN2: one block per row (1024 cols) ----------------
__global__ __launch_bounds__(256) void k_ln2(const float* __restrict__ g1,
                                             const float* __restrict__ lng,
                                             const float* __restrict__ lnb,
                                             float* __restrict__ h2) {
    int b = blockIdx.x, tid = threadIdx.x;
    float v[4];
    float s = 0.f, s2 = 0.f;
#pragma unroll
    for (int j = 0; j < 4; ++j) {
        int nidx = tid + 256 * j;
        float x = g1[b * H4 + nidx];
        v[j] = x;
        s += x; s2 += x * x;
    }
#pragma unroll
    for (int off = 32; off > 0; off >>= 1) {
        s  += __shfl_down(s, off);
        s2 += __shfl_down(s2, off);
    }
    __shared__ float ls[4], ls2[4], smu, srs;
    int wave = tid >> 6;
    if ((tid & 63) == 0) { ls[wave] = s; ls2[wave] = s2; }
    __syncthreads();
    if (tid == 0) {
        float S  = ls[0] + ls[1] + ls[2] + ls[3];
        float S2 = ls2[0] + ls2[1] + ls2[2] + ls2[3];
        float mu = S / (float)H4;
        float var = S2 / (float)H4 - mu * mu;
        smu = mu;
        srs = rsqrtf(var + 1e-5f);
    }
    __syncthreads();
    float mu = smu, rs = srs;
#pragma unroll
    for (int j = 0; j < 4; ++j) {
        int nidx = tid + 256 * j;
        h2[b * H4 + nidx] = (v[j] - mu) * rs * lng[nidx] + lnb[nidx];
    }
}

// ---------------- launch ----------------
extern "C" void kernel_launch(void* const* d_in, const int* in_sizes, int n_in,
                              void* d_out, int out_size, void* d_ws, size_t ws_size,
                              hipStream_t stream) {
    (void)in_sizes; (void)n_in; (void)out_size;
    const int*   tags  = (const int*)d_in[0];
    const float* fc    = (const float*)d_in[1];
    const float* ln_g  = (const float*)d_in[2];
    const float* ln_b  = (const float*)d_in[3];
    const float* w1    = (const float*)d_in[4];
    const float* b1    = (const float*)d_in[5];
    const float* ln2_g = (const float*)d_in[6];
    const float* ln2_b = (const float*)d_in[7];
    const float* we1   = (const float*)d_in[8];
    const float* be1   = (const float*)d_in[9];
    const float* we2   = (const float*)d_in[10];
    const float* be2   = (const float*)d_in[11];
    const float* wd1   = (const float*)d_in[12];
    const float* bd1   = (const float*)d_in[13];
    const float* wd2   = (const float*)d_in[14];
    const float* bd2   = (const float*)d_in[15];

    float* out = (float*)d_out;
    float* y   = out;                              // 64*20001
    float* enc = out + (size_t)BATCH * NT1;        // 64*256
    float* dec = enc + BATCH * HD;                 // 64*20001

    char* ws = (char*)d_ws;
    size_t off = 0;
    float* g1     = (float*)(ws + off); off += (size_t)BATCH * H4 * 4;
    float* h2     = (float*)(ws + off); off += (size_t)BATCH * H4 * 4;
    float* g2     = (float*)(ws + off); off += (size_t)BATCH * H4 * 4;
    float* dd     = (float*)(ws + off); off += (size_t)BATCH * H4 * 4;
    float* arena  = (float*)(ws + off);
    size_t avail  = (ws_size > off) ? (ws_size - off) : 0;

    // split-K tiers (ws_size constant across calls -> deterministic)
    const size_t MB = 1024 * 1024;
    int KS5;
    if (avail >= 45 * MB)      { KS5 = 8; }   // arenas 32.8 / 41.4 MB
    else if (avail >= 33 * MB) { KS5 = 4; }
    else if (avail >= 17 * MB) { KS5 = 4; }
    else                       { KS5 = 2; }
    int kpb5 = H4 / KS5;

    // fused: scatter + LN1 stats + LN1 apply (LDS histogram, no global counts)
    k_ln1_fused<<<64, 1024, 0, stream>>>(tags, fc, ln_g, ln_b, y);

    // GEMM1: yn[64,20000] @ w1[1:,1024]; fc-column folded into reduce as rank-1
    k_gemm<0><<<dim3(4, 125), 256, 0, stream>>>(y + 1, NT1, w1 + H4, H4, arena, H4, 160);
    k_reduce<true><<<dim3(4, 64), 256, 0, stream>>>(arena, 125, b1, w1, fc, g1, H4, H4);
    k_ln2<<<64, 256, 0, stream>>>(g1, ln2_g, ln2_b, h2);

    // GEMM2: h2 @ we1[1024,1024]
    k_gemm<0><<<dim3(4, 32), 256, 0, stream>>>(h2, H4, we1, H4, arena, H4, 32);
    k_reduce<true><<<dim3(4, 64), 256, 0, stream>>>(arena, 32, be1, nullptr, nullptr, g2, H4, H4);

    // GEMM3: g2 @ we2[1024,256]
    k_gemm<0><<<dim3(1, 32), 256, 0, stream>>>(g2, H4, we2, HD, arena, HD, 32);
    k_reduce<false><<<dim3(1, 64), 256, 0, stream>>>(arena, 32, be2, nullptr, nullptr, enc, HD, HD);

    // GEMM4: enc @ wd1[256,1024]
    k_gemm<0><<<dim3(4, 16), 256, 0, stream>>>(enc, HD, wd1, H4, arena, H4, 16);
    k_reduce<true><<<dim3(4, 64), 256, 0, stream>>>(arena, 16, bd1, nullptr, nullptr, dd, H4, H4);

    // GEMM5: dd @ wd2[1024,20001]  (odd ldw -> PATH 1)
    k_gemm<1><<<dim3(79, KS5), 256, 0, stream>>>(dd, H4, wd2, NT1, arena, NT1, kpb5);
    k_reduce_v4<<<dim3(20, 64), 256, 0, stream>>>(arena, KS5, bd2, dec, NT1, NT1);
}

// Round 5
// 314.856 us; speedup vs baseline: 1.0943x; 1.0167x over previous
//
#include <hip/hip_runtime.h>
#include <math.h>

#define NUM_TAGS 20000
#define BATCH 64
#define H4 1024
#define HD 256
#define NT1 20001   // NUM_TAGS + 1

__device__ __forceinline__ float gelu_exact(float x) {
    return 0.5f * x * (1.0f + erff(x * 0.7071067811865476f));
}

// 4-byte-aligned float4 (rows can be misaligned: ld=20001)
struct F4 { float x, y, z, w; };

// ---- async global->LDS (gfx950). LDS dest = wave-uniform base + lane*size.
typedef const __attribute__((address_space(1))) void* gp_t;
typedef __attribute__((address_space(3))) void* lp_t;
__device__ __forceinline__ void async_ld4(const float* g, float* lds_base) {
    __builtin_amdgcn_global_load_lds((gp_t)g, (lp_t)lds_base, 4, 0, 0);
}
__device__ __forceinline__ void async_ld16(const float* g, float* lds_base) {
    __builtin_amdgcn_global_load_lds((gp_t)g, (lp_t)lds_base, 16, 0, 0);
}

// ---------- fused: scatter(dedup) + LN1 stats + LN1 apply, all in LDS -------
// One block per batch row b. 20000-bin histogram lives in LDS (80 KB);
// no global counts buffer, no memset, no global atomics, no re-reads.
__global__ __launch_bounds__(1024) void k_ln1_fused(const int* __restrict__ tags,
                                                    const float* __restrict__ fc,
                                                    const float* __restrict__ lng,
                                                    const float* __restrict__ lnb,
                                                    float* __restrict__ y) {
    __shared__ int hist[NUM_TAGS];
    __shared__ float ls[16], ls2[16], smu, srs;
    const int b = blockIdx.x, tid = threadIdx.x;

    for (int t = tid; t < NUM_TAGS; t += 1024) hist[t] = 0;
    __syncthreads();

    if (tid < 128) {
        const int* tp = tags + ((size_t)(b * 128 + tid) << 4);
        int t[16];
#pragma unroll
        for (int i = 0; i < 16; ++i) t[i] = tp[i];
#pragma unroll
        for (int i = 0; i < 16; ++i) {
            bool dup = false;
            for (int j = 0; j < i; ++j) dup = dup || (t[j] == t[i]);
            if (!dup) atomicAdd(&hist[t[i]], 1);
        }
    }
    __syncthreads();

    float s = 0.f, s2 = 0.f;
    for (int t = tid; t < NUM_TAGS; t += 1024) {
        float v = (float)hist[t];
        s += v; s2 += v * v;
    }
#pragma unroll
    for (int off = 32; off > 0; off >>= 1) {
        s  += __shfl_down(s, off);
        s2 += __shfl_down(s2, off);
    }
    int wave = tid >> 6;
    if ((tid & 63) == 0) { ls[wave] = s; ls2[wave] = s2; }
    __syncthreads();
    if (tid == 0) {
        float S = 0.f, S2 = 0.f;
#pragma unroll
        for (int i = 0; i < 16; ++i) { S += ls[i]; S2 += ls2[i]; }
        float mu = S / (float)NUM_TAGS;
        float var = S2 / (float)NUM_TAGS - mu * mu;
        smu = mu;
        srs = rsqrtf(var + 1e-5f);
    }
    __syncthreads();
    float mu = smu, rs = srs;

    float* yrow = y + (size_t)b * NT1;
    if (tid == 0) yrow[0] = fc[b] * 0.01f;
    for (int t = tid; t < NUM_TAGS; t += 1024) {
        float v = (float)hist[t];
        yrow[1 + t] = (v - mu) * rs * lng[t] + lnb[t];
    }
}

// ---------------- async 4-buffer deep-pipelined split-K GEMM, 128-col tiles -
// P[(bx*KS+ky)][64][128] = A[64, kslice] @ W[kslice, 128cols]
// 256 thr: tn=tid&15 (cols tn*4..+3 and 64+tn*4..+3), tb=tid>>4 (4 rows each).
// BK=8, 4 LDS buffers (24 KB total), depth-2 prefetch, counted vmcnt.
// A LDS layout [k4][row][klo] (k4*256+row*4+klo): float4 A-read hits 4
// DISTINCT banks (rows r,r+4,r+8,r+12 -> banks b,b+16,b,b+16 = 2-way free).
// W reads: 16 lanes x 16B contiguous (256B) -> 2-way broadcast, free.
// Requires: kpb % 8 == 0, all K-slices full.
// PATH 0: W rows 16B-aligned (ldw%4==0, N%128==0): 1 async_ld16/thr/chunk.
// PATH 1: dword W loads, col clamped to N-1 (odd ldw): 4 async_ld4/thr/chunk.
// Loads per thread per chunk L: PATH0 = 2(A)+1(W) = 3; PATH1 = 2(A)+4(W) = 6.
// launch_bounds(256,2): (256,4) forced 64 VGPR -> 94 MB scratch spill
// (round-1 disaster). Keep (256,2); HW can still fit >2 blocks/CU.
template <int PATH>
__global__ __launch_bounds__(256, 2) void k_gemm(const float* __restrict__ A, int lda,
                                                 const float* __restrict__ W, int ldw,
                                                 float* __restrict__ P,
                                                 int N, int kpb) {
    __shared__ __align__(16) float As[4][512];    // [k4][row][klo]
    __shared__ __align__(16) float Ws[4][1024];   // [kk][col] : kk*128 + col
    const int tid = threadIdx.x;
    const int lane = tid & 63, wid = tid >> 6;
    const int tn = tid & 15, tb = tid >> 4;
    const int n0 = blockIdx.x * 128;
    const int kstart = blockIdx.y * kpb;
    const int nchunk = kpb >> 3;

    float acc[4][8];
#pragma unroll
    for (int i = 0; i < 4; ++i)
#pragma unroll
        for (int j = 0; j < 8; ++j) acc[i][j] = 0.f;

    // ---- issue chunk c into buffer b (async DMA) ----
    auto issue = [&](int b, int c) {
        int k0 = kstart + c * 8;
        // A tile: 64 rows x 8 kk = 512 dwords; d -> k4=d>>8, row=(d&255)>>2,
        // klo=d&3  (dest layout As[k4][row][klo], contiguous in d)
#pragma unroll
        for (int j = 0; j < 2; ++j) {
            int d0 = j * 256 + wid * 64;
            int d = d0 + lane;
            int k4 = d >> 8, row = (d & 255) >> 2, klo = d & 3;
            async_ld4(A + (size_t)row * lda + k0 + k4 * 4 + klo, &As[b][d0]);
        }
        if (PATH == 0) {
            // W tile: 8 rows x 128 cols = 256 16B-granules; g=tid -> kk=g>>5, c4=g&31
            int kk = tid >> 5, c4 = tid & 31;
            async_ld16(W + (size_t)(k0 + kk) * ldw + n0 + c4 * 4, &Ws[b][wid * 256]);
        } else {
            // W tile: 1024 dwords; d -> kk=d>>7, cc=d&127 (col clamped)
#pragma unroll
            for (int j = 0; j < 4; ++j) {
                int d = j * 256 + tid;
                int kk = d >> 7, cc = d & 127;
                async_ld4(W + (size_t)(k0 + kk) * ldw + min(n0 + cc, N - 1),
                          &Ws[b][j * 256 + wid * 64]);
            }
        }
    };

    issue(0, 0);
    if (nchunk > 1) issue(1, 1);

    for (int c = 0; c < nchunk; ++c) {
        if (c + 2 < nchunk) issue((c + 2) & 3, c + 2);
        // Counted wait: keep up to 2 chunks' loads in flight across the barrier.
        int ahead = nchunk - 1 - c;
        if (PATH == 0) {
            if (ahead >= 2)      asm volatile("s_waitcnt vmcnt(6)"  ::: "memory");
            else if (ahead == 1) asm volatile("s_waitcnt vmcnt(3)"  ::: "memory");
            else                 asm volatile("s_waitcnt vmcnt(0)"  ::: "memory");
        } else {
            if (ahead >= 2)      asm volatile("s_waitcnt vmcnt(12)" ::: "memory");
            else if (ahead == 1) asm volatile("s_waitcnt vmcnt(6)"  ::: "memory");
            else                 asm volatile("s_waitcnt vmcnt(0)"  ::: "memory");
        }
        __builtin_amdgcn_s_barrier();          // all waves' chunk-c loads landed
        asm volatile("" ::: "memory");         // no LDS access hoisted above

        const float* Ab = As[c & 3];
        const float* Wb = Ws[c & 3];
        __builtin_amdgcn_s_setprio(1);
#pragma unroll
        for (int k4 = 0; k4 < 2; ++k4) {
            float4 a4[4];
#pragma unroll
            for (int i = 0; i < 4; ++i)
                a4[i] = *(const float4*)&Ab[k4 * 256 + (tb * 4 + i) * 4];
#pragma unroll
            for (int kl = 0; kl < 4; ++kl) {
                const float4 w0 = *(const float4*)&Wb[(k4 * 4 + kl) * 128 + tn * 4];
                const float4 w1 = *(const float4*)&Wb[(k4 * 4 + kl) * 128 + 64 + tn * 4];
#pragma unroll
                for (int i = 0; i < 4; ++i) {
                    float av = (kl == 0) ? a4[i].x : (kl == 1) ? a4[i].y
                             : (kl == 2) ? a4[i].z : a4[i].w;
                    acc[i][0] = fmaf(av, w0.x, acc[i][0]);
                    acc[i][1] = fmaf(av, w0.y, acc[i][1]);
                    acc[i][2] = fmaf(av, w0.z, acc[i][2]);
                    acc[i][3] = fmaf(av, w0.w, acc[i][3]);
                    acc[i][4] = fmaf(av, w1.x, acc[i][4]);
                    acc[i][5] = fmaf(av, w1.y, acc[i][5]);
                    acc[i][6] = fmaf(av, w1.z, acc[i][6]);
                    acc[i][7] = fmaf(av, w1.w, acc[i][7]);
                }
            }
        }
        __builtin_amdgcn_s_setprio(0);
        asm volatile("" ::: "memory");         // no LDS access sunk below
    }

    float* Pp = P + ((size_t)blockIdx.x * gridDim.y + blockIdx.y) * 8192;
#pragma unroll
    for (int i = 0; i < 4; ++i) {
        int row = tb * 4 + i;
        float4 v0 = {acc[i][0], acc[i][1], acc[i][2], acc[i][3]};
        float4 v1 = {acc[i][4], acc[i][5], acc[i][6], acc[i][7]};
        *(float4*)&Pp[row * 128 + tn * 4]      = v0;
        *(float4*)&Pp[row * 128 + 64 + tn * 4] = v1;
    }
}

// ---------------- reduce partials + bias (+gelu) ---------------------------
template <bool GELU>
__global__ __launch_bounds__(256) void k_reduce(const float* __restrict__ P, int KS,
                                                const float* __restrict__ bias,
                                                float* __restrict__ out, int ldo, int N) {
    int b = blockIdx.y;
    int n = blockIdx.x * 256 + threadIdx.x;
    if (n >= N) return;
    int nb = n >> 7, col = n & 127;
    const float* p = P + (size_t)nb * KS * 8192 + b * 128 + col;
    float s0 = 0.f, s1 = 0.f, s2 = 0.f, s3 = 0.f;
    int k = 0;
    for (; k + 3 < KS; k += 4) {
        s0 += p[(size_t)(k + 0) * 8192];
        s1 += p[(size_t)(k + 1) * 8192];
        s2 += p[(size_t)(k + 2) * 8192];
        s3 += p[(size_t)(k + 3) * 8192];
    }
    for (; k < KS; ++k) s0 += p[(size_t)k * 8192];
    float s = (s0 + s1) + (s2 + s3) + bias[n];
    if (GELU) s = gelu_exact(s);
    out[(size_t)b * ldo + n] = s;
}

// ------- fused: reduce GEMM1 partials + bias + rank1(fc) + gelu + LN2 ------
// One block per batch row (1024 threads = 1024 cols).
__global__ __launch_bounds__(1024) void k_red_ln2(const float* __restrict__ P, int KS,
                                                  const float* __restrict__ bias,
                                                  const float* __restrict__ r1row,
                                                  const float* __restrict__ fc,
                                                  const float* __restrict__ lng,
                                                  const float* __restrict__ lnb,
                                                  float* __restrict__ h2) {
    const int b = blockIdx.x, n = threadIdx.x;
    int nb = n >> 7, col = n & 127;
    const float* p = P + (size_t)nb * KS * 8192 + b * 128 + col;
    float s0 = 0.f, s1 = 0.f, s2v = 0.f, s3 = 0.f;
    int k = 0;
    for (; k + 3 < KS; k += 4) {
        s0  += p[(size_t)(k + 0) * 8192];
        s1  += p[(size_t)(k + 1) * 8192];
        s2v += p[(size_t)(k + 2) * 8192];
        s3  += p[(size_t)(k + 3) * 8192];
    }
    for (; k < KS; ++k) s0 += p[(size_t)k * 8192];
    float v = (s0 + s1) + (s2v + s3) + bias[n] + fc[b] * 0.01f * r1row[n];
    v = gelu_exact(v);

    // LN over the 1024 cols
    float s = v, s2 = v * v;
#pragma unroll
    for (int off = 32; off > 0; off >>= 1) {
        s  += __shfl_down(s, off);
        s2 += __shfl_down(s2, off);
    }
    __shared__ float ls[16], ls2[16], smu, srs;
    int wave = n >> 6;
    if ((n & 63) == 0) { ls[wave] = s; ls2[wave] = s2; }
    __syncthreads();
    if (n == 0) {
        float S = 0.f, S2 = 0.f;
#pragma unroll
        for (int i = 0; i < 16; ++i) { S += ls[i]; S2 += ls2[i]; }
        float mu = S / (float)H4;
        float var = S2 / (float)H4 - mu * mu;
        smu = mu;
        srs = rsqrtf(var + 1e-5f);
    }
    __syncthreads();
    h2[(size_t)b * H4 + n] = (v - smu) * srs * lng[n] + lnb[n];
}

// ---------------- vectorized reduce (bias only, no gelu) for wide N --------
__global__ __launch_bounds__(256) void k_reduce_v4(const float* __restrict__ P, int KS,
                                                   const float* __restrict__ bias,
                                                   float* __restrict__ out, int ldo, int N) {
    int b = blockIdx.y;
    int n = (blockIdx.x * 256 + threadIdx.x) * 4;
    if (n >= N) return;
    int nb = n >> 7, col = n & 127;
    const float* p = P + (size_t)nb * KS * 8192 + b * 128 + col;
    if (n + 3 < N) {
        float sx = 0.f, sy = 0.f, sz = 0.f, sw = 0.f;
        for (int k = 0; k < KS; ++k) {
            float4 v = *(const float4*)&p[(size_t)k * 8192];
            sx += v.x; sy += v.y; sz += v.z; sw += v.w;
        }
        F4 bi = *(const F4*)&bias[n];
        F4 r = {sx + bi.x, sy + bi.y, sz + bi.z, sw + bi.w};
        *(F4*)&out[(size_t)b * ldo + n] = r;   // ldo odd -> 4B-aligned store
    } else {
        for (int j = 0; n + j < N; ++j) {
            float s = 0.f;
            for (int k = 0; k < KS; ++k) s += p[(size_t)k * 8192 + j];
            out[(size_t)b * ldo + n + j] = s + bias[n + j];
        }
    }
}

// ---------------- launch ----------------
extern "C" void kernel_launch(void* const* d_in, const int* in_sizes, int n_in,
                              void* d_out, int out_size, void* d_ws, size_t ws_size,
                              hipStream_t stream) {
    (void)in_sizes; (void)n_in; (void)out_size;
    const int*   tags  = (const int*)d_in[0];
    const float* fc    = (const float*)d_in[1];
    const float* ln_g  = (const float*)d_in[2];
    const float* ln_b  = (const float*)d_in[3];
    const float* w1    = (const float*)d_in[4];
    const float* b1    = (const float*)d_in[5];
    const float* ln2_g = (const float*)d_in[6];
    const float* ln2_b = (const float*)d_in[7];
    const float* we1   = (const float*)d_in[8];
    const float* be1   = (const float*)d_in[9];
    const float* we2   = (const float*)d_in[10];
    const float* be2   = (const float*)d_in[11];
    const float* wd1   = (const float*)d_in[12];
    const float* bd1   = (const float*)d_in[13];
    const float* wd2   = (const float*)d_in[14];
    const float* bd2   = (const float*)d_in[15];

    float* out = (float*)d_out;
    float* y   = out;                              // 64*20001
    float* enc = out + (size_t)BATCH * NT1;        // 64*256
    float* dec = enc + BATCH * HD;                 // 64*20001

    char* ws = (char*)d_ws;
    size_t off = 0;
    float* h2     = (float*)(ws + off); off += (size_t)BATCH * H4 * 4;
    float* g2     = (float*)(ws + off); off += (size_t)BATCH * H4 * 4;
    float* dd     = (float*)(ws + off); off += (size_t)BATCH * H4 * 4;
    float* arena  = (float*)(ws + off);
    size_t avail  = (ws_size > off) ? (ws_size - off) : 0;

    // split-K tier for GEMM5 (ws_size constant across calls -> deterministic)
    const size_t MB = 1024 * 1024;
    int KS5;
    if (avail >= 45 * MB)      { KS5 = 8; }   // GEMM5 arena 41.1 MB; GEMM1 32.8 MB
    else if (avail >= 33 * MB) { KS5 = 4; }
    else                       { KS5 = 2; }
    int kpb5 = H4 / KS5;

    // fused: scatter + LN1 stats + LN1 apply (LDS histogram, no global counts)
    k_ln1_fused<<<64, 1024, 0, stream>>>(tags, fc, ln_g, ln_b, y);

    // GEMM1: yn[64,20000] @ w1[1:,1024]; fc column folded into fused reduce
    k_gemm<0><<<dim3(8, 125), 256, 0, stream>>>(y + 1, NT1, w1 + H4, H4, arena, H4, 160);
    k_red_ln2<<<64, 1024, 0, stream>>>(arena, 125, b1, w1, fc, ln2_g, ln2_b, h2);

    // GEMM2: h2 @ we1[1024,1024]
    k_gemm<0><<<dim3(8, 32), 256, 0, stream>>>(h2, H4, we1, H4, arena, H4, 32);
    k_reduce<true><<<dim3(4, 64), 256, 0, stream>>>(arena, 32, be1, g2, H4, H4);

    // GEMM3: g2 @ we2[1024,256]  (KS=64 for occupancy)
    k_gemm<0><<<dim3(2, 64), 256, 0, stream>>>(g2, H4, we2, HD, arena, HD, 16);
    k_reduce<false><<<dim3(1, 64), 256, 0, stream>>>(arena, 64, be2, enc, HD, HD);

    // GEMM4: enc @ wd1[256,1024]
    k_gemm<0><<<dim3(8, 16), 256, 0, stream>>>(enc, HD, wd1, H4, arena, H4, 16);
    k_reduce<true><<<dim3(4, 64), 256, 0, stream>>>(arena, 16, bd1, dd, H4, H4);

    // GEMM5: dd @ wd2[1024,20001]  (odd ldw -> PATH 1)
    k_gemm<1><<<dim3(157, KS5), 256, 0, stream>>>(dd, H4, wd2, NT1, arena, NT1, kpb5);
    k_reduce_v4<<<dim3(20, 64), 256, 0, stream>>>(arena, KS5, bd2, dec, NT1, NT1);
}